// Round 7
// baseline (456.086 us; speedup 1.0000x reference)
//
#include <hip/hip_runtime.h>
#include <hip/hip_bf16.h>

#define CIN   512
#define COUT  512
#define LEN   8192
#define NB    16
#define KW    3
#define PROWS 8200          // padded l-rows per batch (p = l+1, l=-1..8193+slack)

#define WB_ELEMS (COUT * CIN * KW)
#define WB_BYTES ((size_t)WB_ELEMS * 2)
#define XS_BYTES ((size_t)NB * PROWS * CIN * 2)

// main kernel: 256x256 tile, BK=64, 8 waves (2Mx4N), 8-phase + safe frag prefetch
#define BM2 256
#define BN2 256
#define BK3 64
#define NT  ((CIN / BK3) * KW)        // 24 K-tiles, tap innermost
#define TILE3 (BM2 * BK3 * 2)         // 32 KB per operand tile

typedef __attribute__((ext_vector_type(4))) float f32x4;
typedef __attribute__((ext_vector_type(8))) short bf16x8;

static __device__ __forceinline__ unsigned short f2bf(float f) {
    union { float f; unsigned u; } cv; cv.f = f;
    return (unsigned short)((cv.u + 0x7fffu + ((cv.u >> 16) & 1u)) >> 16);
}

// ---- weight dequant-reorder: qweight[co][ci][t] (int32) -> wb[co][t*512+ci] (bf16) ----
__global__ __launch_bounds__(256) void wconv_kernel(const int* __restrict__ q,
                                                    unsigned short* __restrict__ wb) {
    int idx = blockIdx.x * 256 + threadIdx.x;
    if (idx >= WB_ELEMS) return;
    int co = idx / (KW * CIN);
    int r  = idx - co * (KW * CIN);
    int t  = r >> 9;
    int ci = r & 511;
    wb[idx] = f2bf((float)q[(co * CIN + ci) * KW + t]);
}

// ---- x prepass: fp32 [b][ci][l] -> bf16 [b][1+l][ci]; also zero halo rows ----
__global__ __launch_bounds__(256) void xprep_kernel(const float* __restrict__ x,
                                                    unsigned short* __restrict__ xs) {
    __shared__ char T[64 * 132];
    int blk = blockIdx.x;
    int b   = blk >> 10;
    int ci0 = ((blk >> 7) & 7) * 64;
    int l0  = (blk & 127) * 64;
    int tid = threadIdx.x;

    if (l0 == 0 && tid < 64)
        xs[((size_t)b * PROWS + 0) * CIN + ci0 + tid] = 0;
    if (l0 == (LEN - 64) && tid < 64)
        xs[((size_t)b * PROWS + (LEN + 1)) * CIN + ci0 + tid] = 0;

    const float* src = x + ((size_t)b * CIN + ci0) * LEN + l0;
    for (int i = tid; i < 64 * 16; i += 256) {
        int r = i >> 4, c4 = i & 15;
        f32x4 v = *(const f32x4*)(src + (size_t)r * LEN + c4 * 4);
        unsigned lo = (unsigned)f2bf(v[0]) | ((unsigned)f2bf(v[1]) << 16);
        unsigned hi = (unsigned)f2bf(v[2]) | ((unsigned)f2bf(v[3]) << 16);
        char* p = T + r * 132 + c4 * 8;
        *(unsigned*)p       = lo;
        *(unsigned*)(p + 4) = hi;
    }
    __syncthreads();
    unsigned short* dst = xs + ((size_t)b * PROWS + 1 + l0) * CIN + ci0;
    for (int i = tid; i < 64 * 8; i += 256) {
        int l = i >> 3, c8 = i & 7;
        union { bf16x8 v; unsigned short s[8]; } pk;
        #pragma unroll
        for (int j = 0; j < 8; ++j)
            pk.s[j] = *(const unsigned short*)(T + (c8 * 8 + j) * 132 + l * 2);
        *(bf16x8*)(dst + (size_t)l * CIN + c8 * 8) = pk.v;
    }
}

// ---- main conv: 8-phase counted-vmcnt + cross-wave-safe one-phase-ahead frag prefetch ----
// Invariant: every ds_read of a staged region happens AFTER a barrier that follows
// all waves' vmcnt-drain of that unit (vmcnt is per-wave; staging is cooperative).
__global__ __launch_bounds__(512, 2) void conv_kernel(
    const unsigned short* __restrict__ xs,
    const unsigned short* __restrict__ wb,
    const float* __restrict__ scale_p,
    const float* __restrict__ bias,
    float* __restrict__ out)
{
    __shared__ char sA[2][TILE3];    // 2 x 32 KB
    __shared__ char sB[2][TILE3];    // 2 x 32 KB   (128 KiB total)

    const int bid = blockIdx.x;
    const int logical = (bid & 7) * 128 + (bid >> 3);   // XCD swizzle, 1024 = 8*128
    const int co_tile = logical & 1;
    const int l_tile  = logical >> 1;
    const int b   = l_tile >> 5;
    const int l0  = (l_tile & 31) * BN2;
    const int co0 = co_tile * BM2;

    const int tid  = threadIdx.x;
    const int lane = tid & 63;
    const int wid  = tid >> 6;
    const int wr   = wid >> 2;        // 0..1
    const int wc   = wid & 3;         // 0..3
    const int lhi  = lane >> 4;
    const int llo  = lane & 15;

    f32x4 acc[8][4] = {};             // row = m*32 + wr*16 (interleaved map)

    const char* xsB = (const char*)(xs + ((size_t)b * PROWS + l0) * CIN);
    const char* wbB = (const char*)wb + (size_t)co0 * (KW * CIN * 2);

    // ---- per-thread stage source pointers (incremental; delta per K-tile) ----
    const int it0 = tid, it1 = tid + 512;
    const int r0 = it0 >> 3, r1 = it1 >> 3;
    const int sw0 = ((it0 & 7) * 16) ^ ((r0 & 7) << 4);
    const int sw1 = ((it1 & 7) * 16) ^ ((r1 & 7) << 4);
    const char* pBs[4] = { xsB + r0 * 1024 + sw0,          xsB + r1 * 1024 + sw1,
                           xsB + (128 + r0) * 1024 + sw0,  xsB + (128 + r1) * 1024 + sw1 };
    const char* pAs[4] = { wbB + (size_t)r0 * 3072 + sw0,         wbB + (size_t)r1 * 3072 + sw1,
                           wbB + (size_t)(128 + r0) * 3072 + sw0, wbB + (size_t)(128 + r1) * 3072 + sw1 };
    const int d0 = tid * 16, d1 = d0 + 8192;

    // ---- per-thread LDS read bases: off(mq,k) = base_k + mq*4096 ; off(n,k) = base_k + n*2048 ----
    const int s10 = llo & 3, s2 = (llo >> 2) & 1;
    const int constA = (wr * 16 + llo) * 128 + ((lhi ^ s10) << 4);
    const int constB = (wc * 64 + llo) * 128 + ((lhi ^ s10) << 4);
    const char* pA0b = &sA[0][0] + constA + (s2 ? 64 : 0);   // A k=0
    const char* pA1b = &sA[0][0] + constA + (s2 ? 0 : 64);   // A k=1
    const char* pB0b = &sB[0][0] + constB + (s2 ? 64 : 0);   // B k=0
    const char* pB1b = &sB[0][0] + constB + (s2 ? 0 : 64);   // B k=1

#define STAGEU(buf_, u_) do {                                                                \
    const char* s0_; const char* s1_; char* dd_;                                             \
    if ((u_) == 0)      { s0_ = pBs[0]; s1_ = pBs[1]; dd_ = &sB[buf_][0];     }              \
    else if ((u_) == 1) { s0_ = pBs[2]; s1_ = pBs[3]; dd_ = &sB[buf_][16384]; }              \
    else if ((u_) == 2) { s0_ = pAs[0]; s1_ = pAs[1]; dd_ = &sA[buf_][0];     }              \
    else                { s0_ = pAs[2]; s1_ = pAs[3]; dd_ = &sA[buf_][16384]; }              \
    __builtin_amdgcn_global_load_lds(                                                        \
        (const __attribute__((address_space(1))) unsigned int*)s0_,                          \
        (__attribute__((address_space(3))) unsigned int*)(dd_ + d0), 16, 0, 0);              \
    __builtin_amdgcn_global_load_lds(                                                        \
        (const __attribute__((address_space(1))) unsigned int*)s1_,                          \
        (__attribute__((address_space(3))) unsigned int*)(dd_ + d1), 16, 0, 0);              \
    } while (0)

#define RDA(p_, mq_) (*(const bf16x8*)((p_) + (mq_) * 4096))
#define RDB(p_, n_)  (*(const bf16x8*)((p_) + (n_) * 2048))

#define MFMA16(mb_, A0_, A1_, A2_, A3_, B0_, B1_, B2_, B3_) do {                             \
    __builtin_amdgcn_s_setprio(1);                                                           \
    acc[(mb_)+0][0] = __builtin_amdgcn_mfma_f32_16x16x32_bf16(A0_, B0_, acc[(mb_)+0][0],0,0,0); \
    acc[(mb_)+0][1] = __builtin_amdgcn_mfma_f32_16x16x32_bf16(A0_, B1_, acc[(mb_)+0][1],0,0,0); \
    acc[(mb_)+0][2] = __builtin_amdgcn_mfma_f32_16x16x32_bf16(A0_, B2_, acc[(mb_)+0][2],0,0,0); \
    acc[(mb_)+0][3] = __builtin_amdgcn_mfma_f32_16x16x32_bf16(A0_, B3_, acc[(mb_)+0][3],0,0,0); \
    acc[(mb_)+1][0] = __builtin_amdgcn_mfma_f32_16x16x32_bf16(A1_, B0_, acc[(mb_)+1][0],0,0,0); \
    acc[(mb_)+1][1] = __builtin_amdgcn_mfma_f32_16x16x32_bf16(A1_, B1_, acc[(mb_)+1][1],0,0,0); \
    acc[(mb_)+1][2] = __builtin_amdgcn_mfma_f32_16x16x32_bf16(A1_, B2_, acc[(mb_)+1][2],0,0,0); \
    acc[(mb_)+1][3] = __builtin_amdgcn_mfma_f32_16x16x32_bf16(A1_, B3_, acc[(mb_)+1][3],0,0,0); \
    acc[(mb_)+2][0] = __builtin_amdgcn_mfma_f32_16x16x32_bf16(A2_, B0_, acc[(mb_)+2][0],0,0,0); \
    acc[(mb_)+2][1] = __builtin_amdgcn_mfma_f32_16x16x32_bf16(A2_, B1_, acc[(mb_)+2][1],0,0,0); \
    acc[(mb_)+2][2] = __builtin_amdgcn_mfma_f32_16x16x32_bf16(A2_, B2_, acc[(mb_)+2][2],0,0,0); \
    acc[(mb_)+2][3] = __builtin_amdgcn_mfma_f32_16x16x32_bf16(A2_, B3_, acc[(mb_)+2][3],0,0,0); \
    acc[(mb_)+3][0] = __builtin_amdgcn_mfma_f32_16x16x32_bf16(A3_, B0_, acc[(mb_)+3][0],0,0,0); \
    acc[(mb_)+3][1] = __builtin_amdgcn_mfma_f32_16x16x32_bf16(A3_, B1_, acc[(mb_)+3][1],0,0,0); \
    acc[(mb_)+3][2] = __builtin_amdgcn_mfma_f32_16x16x32_bf16(A3_, B2_, acc[(mb_)+3][2],0,0,0); \
    acc[(mb_)+3][3] = __builtin_amdgcn_mfma_f32_16x16x32_bf16(A3_, B3_, acc[(mb_)+3][3],0,0,0); \
    __builtin_amdgcn_s_setprio(0);                                                           \
    } while (0)

#define BAR()    __builtin_amdgcn_s_barrier()
#define SCHED0() __builtin_amdgcn_sched_barrier(0)

    // prologue: stage all 4 units of tile 0; drain u0-u2 (own), BAR -> globally landed
    STAGEU(0, 0); STAGEU(0, 1); STAGEU(0, 2); STAGEU(0, 3);
    {
        #pragma unroll
        for (int i = 0; i < 4; ++i) { pBs[i] += 1024; pAs[i] += 1024; }
    }
    int tapn = 1;                     // tap of next-staged tile (tile 1)
    asm volatile("s_waitcnt vmcnt(2)" ::: "memory");
    BAR(); SCHED0();

    // fragment registers (statically named; aX/aY alternate, bA=k0 set, bB=k1 set)
    bf16x8 aX0, aX1, aX2, aX3;
    bf16x8 aY0, aY1, aY2, aY3;
    bf16x8 bA0, bA1, bA2, bA3;
    bf16x8 bB0, bB1, bB2, bB3;

    // preload tile0 p0 fragments (u2 / u0+u1 regions -> globally landed)
    aX0 = RDA(pA0b, 0); aX1 = RDA(pA0b, 1); aX2 = RDA(pA0b, 2); aX3 = RDA(pA0b, 3);
    bA0 = RDB(pB0b, 0); bA1 = RDB(pB0b, 1); bA2 = RDB(pB0b, 2); bA3 = RDB(pB0b, 3);

    #pragma unroll 1
    for (int c = 0; c < NT - 1; ++c) {
        const int buf = c & 1;
        const int nb  = buf ^ 1;
        const int bufo = buf << 15, nbo = nb << 15;
        const char* cpA0 = pA0b + bufo;
        const char* cpA1 = pA1b + bufo;
        const char* cpB1 = pB1b + bufo;
        const char* npA0 = pA0b + nbo;
        const char* npB0 = pB0b + nbo;

        // ---- p0: stage u0'; post-BAR prefetch {A(mq0-3,k1), Bk1}; MFMA(aX, bA) ----
        SCHED0();
        STAGEU(nb, 0);
        SCHED0();
        BAR(); SCHED0();
        aY0 = RDA(cpA1, 0); aY1 = RDA(cpA1, 1); aY2 = RDA(cpA1, 2); aY3 = RDA(cpA1, 3);
        bB0 = RDB(cpB1, 0); bB1 = RDB(cpB1, 1); bB2 = RDB(cpB1, 2); bB3 = RDB(cpB1, 3);
        SCHED0();
        MFMA16(0, aX0, aX1, aX2, aX3, bA0, bA1, bA2, bA3);
        BAR();
        // ---- p1: stage u1'; drain u3(cur) own + BAR => u3 global; prefetch {A(mq4-7,k0)} ----
        SCHED0();
        STAGEU(nb, 1);
        asm volatile("s_waitcnt vmcnt(4)" ::: "memory");
        SCHED0();
        BAR(); SCHED0();
        aX0 = RDA(cpA0, 4); aX1 = RDA(cpA0, 5); aX2 = RDA(cpA0, 6); aX3 = RDA(cpA0, 7);
        SCHED0();
        MFMA16(0, aY0, aY1, aY2, aY3, bB0, bB1, bB2, bB3);
        BAR();
        // ---- p2: stage u2'; prefetch {A(mq4-7,k1)} (u3 global since p1); MFMA(aX, bA) ----
        SCHED0();
        STAGEU(nb, 2);
        SCHED0();
        BAR(); SCHED0();
        aY0 = RDA(cpA1, 4); aY1 = RDA(cpA1, 5); aY2 = RDA(cpA1, 6); aY3 = RDA(cpA1, 7);
        SCHED0();
        MFMA16(4, aX0, aX1, aX2, aX3, bA0, bA1, bA2, bA3);
        BAR();
        // ---- p3: stage u3'; drain u0'-u2' own + BAR => global; prefetch next {A'(mq0-3,k0), B'k0} ----
        SCHED0();
        STAGEU(nb, 3);
        asm volatile("s_waitcnt vmcnt(2)" ::: "memory");
        SCHED0();
        BAR(); SCHED0();
        aX0 = RDA(npA0, 0); aX1 = RDA(npA0, 1); aX2 = RDA(npA0, 2); aX3 = RDA(npA0, 3);
        bA0 = RDB(npB0, 0); bA1 = RDB(npB0, 1); bA2 = RDB(npB0, 2); bA3 = RDB(npB0, 3);
        SCHED0();
        MFMA16(4, aY0, aY1, aY2, aY3, bB0, bB1, bB2, bB3);
        BAR();

        // advance stage pointers to tile c+2
        const int kd = (tapn == 2) ? -1920 : 1024;
        tapn = (tapn == 2) ? 0 : tapn + 1;
        #pragma unroll
        for (int i = 0; i < 4; ++i) { pBs[i] += kd; pAs[i] += kd; }
    }
    // ---- peeled tail tile (no stages) ----
    {
        const int bufo = ((NT - 1) & 1) << 15;
        const char* cpA0 = pA0b + bufo;
        const char* cpA1 = pA1b + bufo;
        const char* cpB1 = pB1b + bufo;
        // t-p0
        SCHED0();
        aY0 = RDA(cpA1, 0); aY1 = RDA(cpA1, 1); aY2 = RDA(cpA1, 2); aY3 = RDA(cpA1, 3);
        bB0 = RDB(cpB1, 0); bB1 = RDB(cpB1, 1); bB2 = RDB(cpB1, 2); bB3 = RDB(cpB1, 3);
        SCHED0();
        MFMA16(0, aX0, aX1, aX2, aX3, bA0, bA1, bA2, bA3);
        BAR();
        // t-p1: drain u3(last) own + BAR => global; then read mq4-7
        asm volatile("s_waitcnt vmcnt(0)" ::: "memory");
        BAR(); SCHED0();
        aX0 = RDA(cpA0, 4); aX1 = RDA(cpA0, 5); aX2 = RDA(cpA0, 6); aX3 = RDA(cpA0, 7);
        SCHED0();
        MFMA16(0, aY0, aY1, aY2, aY3, bB0, bB1, bB2, bB3);
        BAR();
        // t-p2
        SCHED0();
        aY0 = RDA(cpA1, 4); aY1 = RDA(cpA1, 5); aY2 = RDA(cpA1, 6); aY3 = RDA(cpA1, 7);
        SCHED0();
        MFMA16(4, aX0, aX1, aX2, aX3, bA0, bA1, bA2, bA3);
        // t-p3
        SCHED0();
        MFMA16(4, aY0, aY1, aY2, aY3, bB0, bB1, bB2, bB3);
    }
#undef STAGEU
#undef RDA
#undef RDB
#undef MFMA16

    const float sc = scale_p[0];
    #pragma unroll
    for (int m = 0; m < 8; ++m) {
        #pragma unroll
        for (int j = 0; j < 4; ++j) {
            int co = co0 + m * 32 + wr * 16 + lhi * 4 + j;
            float bv = bias[co];
            size_t orow = ((size_t)b * COUT + co) * LEN + l0 + wc * 64;
            #pragma unroll
            for (int n = 0; n < 4; ++n)
                out[orow + n * 16 + llo] = sc * acc[m][n][j] + bv;
        }
    }
}

// ---- fallback (no x prepass) — only if ws too small ----
__global__ __launch_bounds__(256, 2) void conv_fb_kernel(
    const float* __restrict__ x,
    const unsigned short* __restrict__ wb,
    const float* __restrict__ scale_p,
    const float* __restrict__ bias,
    float* __restrict__ out)
{
    __shared__ char xT[132 * 128];
    const int bid = blockIdx.x;
    const int logical = (bid & 7) * 512 + (bid >> 3);
    const int co_tile = logical & 3;
    const int n_tile  = logical >> 2;
    const int b   = n_tile >> 6;
    const int l0  = (n_tile & 63) * 128;
    const int co0 = co_tile * 128;
    const int tid  = threadIdx.x;
    const int lane = tid & 63;
    const int wid  = tid >> 6;
    const int wr = wid >> 1, wc = wid & 1;
    const int lhi = lane >> 4;
    const int llo = lane & 15;
    f32x4 acc[4][4] = {};
    const float* xb = x + (size_t)b * CIN * LEN;

    for (int ci0 = 0; ci0 < CIN; ci0 += 64) {
        __syncthreads();
        for (int it = tid; it < 132 * 8; it += 256) {
            int c = it % 132;
            int o = it / 132;
            int l = l0 - 1 + c;
            float v[8];
            if (l >= 0 && l < LEN) {
                const float* src = xb + (size_t)(ci0 + o * 8) * LEN + l;
                #pragma unroll
                for (int j = 0; j < 8; ++j) v[j] = src[(size_t)j * LEN];
            } else {
                #pragma unroll
                for (int j = 0; j < 8; ++j) v[j] = 0.f;
            }
            union { bf16x8 v8; unsigned short s[8]; } pk;
            #pragma unroll
            for (int j = 0; j < 8; ++j) pk.s[j] = f2bf(v[j]);
            int byte = c * 128 + ((o * 16) ^ ((c & 7) << 4));
            *reinterpret_cast<bf16x8*>(xT + byte) = pk.v8;
        }
        __syncthreads();
        #pragma unroll
        for (int t = 0; t < KW; ++t) {
            #pragma unroll
            for (int s = 0; s < 2; ++s) {
                bf16x8 af[4];
                #pragma unroll
                for (int m = 0; m < 4; ++m)
                    af[m] = *reinterpret_cast<const bf16x8*>(
                        wb + (size_t)(co0 + wr * 64 + m * 16 + llo) * (KW * CIN)
                           + t * CIN + ci0 + s * 32 + 8 * lhi);
                bf16x8 bfr[4];
                #pragma unroll
                for (int n = 0; n < 4; ++n) {
                    int col = wc * 64 + n * 16 + llo + t;
                    int byte = col * 128 + (((s * 32 + 8 * lhi) * 2) ^ ((col & 7) << 4));
                    bfr[n] = *reinterpret_cast<const bf16x8*>(xT + byte);
                }
                #pragma unroll
                for (int m = 0; m < 4; ++m)
                    #pragma unroll
                    for (int n = 0; n < 4; ++n)
                        acc[m][n] = __builtin_amdgcn_mfma_f32_16x16x32_bf16(af[m], bfr[n], acc[m][n], 0, 0, 0);
            }
        }
    }
    const float sc = scale_p[0];
    #pragma unroll
    for (int m = 0; m < 4; ++m) {
        #pragma unroll
        for (int j = 0; j < 4; ++j) {
            int co = co0 + wr * 64 + m * 16 + lhi * 4 + j;
            float bv = bias[co];
            size_t orow = ((size_t)b * COUT + co) * LEN + l0 + wc * 64;
            #pragma unroll
            for (int n = 0; n < 4; ++n)
                out[orow + n * 16 + llo] = sc * acc[m][n][j] + bv;
        }
    }
}

extern "C" void kernel_launch(void* const* d_in, const int* in_sizes, int n_in,
                              void* d_out, int out_size, void* d_ws, size_t ws_size,
                              hipStream_t stream) {
    const float* x    = (const float*)d_in[0];
    const int*   qw   = (const int*)d_in[1];
    const float* sc   = (const float*)d_in[2];
    const float* bias = (const float*)d_in[3];
    float* out = (float*)d_out;
    unsigned short* wb = (unsigned short*)d_ws;

    wconv_kernel<<<(WB_ELEMS + 255) / 256, 256, 0, stream>>>(qw, wb);

    if (ws_size >= WB_BYTES + XS_BYTES) {
        unsigned short* xsw = (unsigned short*)((char*)d_ws + WB_BYTES);
        xprep_kernel<<<NB * 8 * (LEN / 64), 256, 0, stream>>>(x, xsw);
        conv_kernel<<<(COUT / BM2) * (NB * LEN / BN2), 512, 0, stream>>>(xsw, wb, sc, bias, out);
    } else {
        conv_fb_kernel<<<4096, 256, 0, stream>>>(x, wb, sc, bias, out);
    }
}

// Round 8
// 290.546 us; speedup vs baseline: 1.5698x; 1.5698x over previous
//
#include <hip/hip_runtime.h>
#include <hip/hip_bf16.h>

#define CIN   512
#define COUT  512
#define LEN   8192
#define NB    16
#define KW    3
#define PROWS 8200          // padded l-rows per batch (p = l+1, l=-1..8193+slack)

#define WB_ELEMS (COUT * CIN * KW)
#define WB_BYTES ((size_t)WB_ELEMS * 2)
#define XS_BYTES ((size_t)NB * PROWS * CIN * 2)

// main kernel: 256x256 tile, BK=64, 8 waves (2Mx4N), 8-phase counted-vmcnt schedule
// (round-4 structure; end-of-phase barriers removed after hazard audit: the only
//  post-barrier code is the register-only MFMA cluster, so skew<=1 phase is safe)
#define BM2 256
#define BN2 256
#define BK3 64
#define NT  ((CIN / BK3) * KW)        // 24 K-tiles, tap innermost
#define TILE3 (BM2 * BK3 * 2)         // 32 KB per operand tile

typedef __attribute__((ext_vector_type(4))) float f32x4;
typedef __attribute__((ext_vector_type(8))) short bf16x8;

static __device__ __forceinline__ unsigned short f2bf(float f) {
    union { float f; unsigned u; } cv; cv.f = f;
    return (unsigned short)((cv.u + 0x7fffu + ((cv.u >> 16) & 1u)) >> 16);
}

// ---- weight dequant-reorder: qweight[co][ci][t] (int32) -> wb[co][t*512+ci] (bf16) ----
__global__ __launch_bounds__(256) void wconv_kernel(const int* __restrict__ q,
                                                    unsigned short* __restrict__ wb) {
    int idx = blockIdx.x * 256 + threadIdx.x;
    if (idx >= WB_ELEMS) return;
    int co = idx / (KW * CIN);
    int r  = idx - co * (KW * CIN);
    int t  = r >> 9;
    int ci = r & 511;
    wb[idx] = f2bf((float)q[(co * CIN + ci) * KW + t]);
}

// ---- x prepass: fp32 [b][ci][l] -> bf16 [b][1+l][ci]; also zero halo rows ----
__global__ __launch_bounds__(256) void xprep_kernel(const float* __restrict__ x,
                                                    unsigned short* __restrict__ xs) {
    __shared__ char T[64 * 132];
    int blk = blockIdx.x;
    int b   = blk >> 10;
    int ci0 = ((blk >> 7) & 7) * 64;
    int l0  = (blk & 127) * 64;
    int tid = threadIdx.x;

    if (l0 == 0 && tid < 64)
        xs[((size_t)b * PROWS + 0) * CIN + ci0 + tid] = 0;
    if (l0 == (LEN - 64) && tid < 64)
        xs[((size_t)b * PROWS + (LEN + 1)) * CIN + ci0 + tid] = 0;

    const float* src = x + ((size_t)b * CIN + ci0) * LEN + l0;
    for (int i = tid; i < 64 * 16; i += 256) {
        int r = i >> 4, c4 = i & 15;
        f32x4 v = *(const f32x4*)(src + (size_t)r * LEN + c4 * 4);
        unsigned lo = (unsigned)f2bf(v[0]) | ((unsigned)f2bf(v[1]) << 16);
        unsigned hi = (unsigned)f2bf(v[2]) | ((unsigned)f2bf(v[3]) << 16);
        char* p = T + r * 132 + c4 * 8;
        *(unsigned*)p       = lo;
        *(unsigned*)(p + 4) = hi;
    }
    __syncthreads();
    unsigned short* dst = xs + ((size_t)b * PROWS + 1 + l0) * CIN + ci0;
    for (int i = tid; i < 64 * 8; i += 256) {
        int l = i >> 3, c8 = i & 7;
        union { bf16x8 v; unsigned short s[8]; } pk;
        #pragma unroll
        for (int j = 0; j < 8; ++j)
            pk.s[j] = *(const unsigned short*)(T + (c8 * 8 + j) * 132 + l * 2);
        *(bf16x8*)(dst + (size_t)l * CIN + c8 * 8) = pk.v;
    }
}

// ---- main conv: 8-phase counted-vmcnt schedule, single barrier per phase ----
__global__ __launch_bounds__(512, 2) void conv_kernel(
    const unsigned short* __restrict__ xs,
    const unsigned short* __restrict__ wb,
    const float* __restrict__ scale_p,
    const float* __restrict__ bias,
    float* __restrict__ out)
{
    __shared__ char sA[2][TILE3];    // 2 x 32 KB
    __shared__ char sB[2][TILE3];    // 2 x 32 KB   (128 KiB total)

    const int bid = blockIdx.x;
    const int logical = (bid & 7) * 128 + (bid >> 3);   // XCD swizzle, 1024 = 8*128
    const int co_tile = logical & 1;
    const int l_tile  = logical >> 1;
    const int b   = l_tile >> 5;
    const int l0  = (l_tile & 31) * BN2;
    const int co0 = co_tile * BM2;

    const int tid  = threadIdx.x;
    const int lane = tid & 63;
    const int wid  = tid >> 6;
    const int wr   = wid >> 2;        // 0..1
    const int wc   = wid & 3;         // 0..3
    const int lhi  = lane >> 4;
    const int llo  = lane & 15;

    f32x4 acc[8][4] = {};             // row = m*32 + wr*16 (interleaved map)

    const char* xsB = (const char*)(xs + ((size_t)b * PROWS + l0) * CIN);
    const char* wbB = (const char*)wb + (size_t)co0 * (KW * CIN * 2);

    // stage unit u of K-tile c into buf: u0=B rows0-127, u1=B rows128-255, u2=A h0, u3=A h1
#define STAGEU(buf_, c_, u_) do {                                                            \
    int tap_ = (c_) % KW;  int ci0_ = ((c_) / KW) * BK3;                                     \
    int rowoff_ = ((u_) & 1) * 128;                                                          \
    const char* src0_; size_t rstride_; char* dst0_;                                         \
    if ((u_) < 2) { src0_ = xsB + ((size_t)(tap_ + rowoff_) * CIN + ci0_) * 2;               \
                    rstride_ = CIN * 2; dst0_ = &sB[buf_][rowoff_ * 128]; }                   \
    else          { src0_ = wbB + (size_t)rowoff_ * (KW * CIN * 2)                           \
                            + ((size_t)tap_ * CIN + ci0_) * 2;                               \
                    rstride_ = KW * CIN * 2; dst0_ = &sA[buf_][rowoff_ * 128]; }             \
    _Pragma("unroll")                                                                        \
    for (int kk_ = 0; kk_ < 2; ++kk_) {                                                      \
        int it_ = tid + kk_ * 512;                                                           \
        int r_ = it_ >> 3, q_ = it_ & 7;                                                     \
        __builtin_amdgcn_global_load_lds(                                                    \
            (const __attribute__((address_space(1))) unsigned int*)                          \
                (src0_ + (size_t)r_ * rstride_ + ((q_ * 16) ^ ((r_ & 7) << 4))),             \
            (__attribute__((address_space(3))) unsigned int*)(dst0_ + it_ * 16),             \
            16, 0, 0);                                                                       \
    } } while (0)

#define LDA(d_, buf_, mq_, k_) do { int row_ = (mq_) * 32 + wr * 16 + llo;                   \
    d_ = *(const bf16x8*)(&sA[buf_][0] + row_ * 128                                          \
                          + (((k_) * 64 + lhi * 16) ^ ((row_ & 7) << 4))); } while (0)
#define LDB(d_, buf_, n_, k_) do { int row_ = wc * 64 + (n_) * 16 + llo;                     \
    d_ = *(const bf16x8*)(&sB[buf_][0] + row_ * 128                                          \
                          + (((k_) * 64 + lhi * 16) ^ ((row_ & 7) << 4))); } while (0)

#define MFMA16(p_) do {                                                                      \
    __builtin_amdgcn_s_setprio(1);                                                           \
    acc[2*(p_)  ][0] = __builtin_amdgcn_mfma_f32_16x16x32_bf16(a0_, bB00, acc[2*(p_)  ][0],0,0,0); \
    acc[2*(p_)  ][1] = __builtin_amdgcn_mfma_f32_16x16x32_bf16(a0_, bB10, acc[2*(p_)  ][1],0,0,0); \
    acc[2*(p_)  ][2] = __builtin_amdgcn_mfma_f32_16x16x32_bf16(a0_, bB20, acc[2*(p_)  ][2],0,0,0); \
    acc[2*(p_)  ][3] = __builtin_amdgcn_mfma_f32_16x16x32_bf16(a0_, bB30, acc[2*(p_)  ][3],0,0,0); \
    acc[2*(p_)+1][0] = __builtin_amdgcn_mfma_f32_16x16x32_bf16(a2_, bB00, acc[2*(p_)+1][0],0,0,0); \
    acc[2*(p_)+1][1] = __builtin_amdgcn_mfma_f32_16x16x32_bf16(a2_, bB10, acc[2*(p_)+1][1],0,0,0); \
    acc[2*(p_)+1][2] = __builtin_amdgcn_mfma_f32_16x16x32_bf16(a2_, bB20, acc[2*(p_)+1][2],0,0,0); \
    acc[2*(p_)+1][3] = __builtin_amdgcn_mfma_f32_16x16x32_bf16(a2_, bB30, acc[2*(p_)+1][3],0,0,0); \
    acc[2*(p_)  ][0] = __builtin_amdgcn_mfma_f32_16x16x32_bf16(a1_, bB01, acc[2*(p_)  ][0],0,0,0); \
    acc[2*(p_)  ][1] = __builtin_amdgcn_mfma_f32_16x16x32_bf16(a1_, bB11, acc[2*(p_)  ][1],0,0,0); \
    acc[2*(p_)  ][2] = __builtin_amdgcn_mfma_f32_16x16x32_bf16(a1_, bB21, acc[2*(p_)  ][2],0,0,0); \
    acc[2*(p_)  ][3] = __builtin_amdgcn_mfma_f32_16x16x32_bf16(a1_, bB31, acc[2*(p_)  ][3],0,0,0); \
    acc[2*(p_)+1][0] = __builtin_amdgcn_mfma_f32_16x16x32_bf16(a3_, bB01, acc[2*(p_)+1][0],0,0,0); \
    acc[2*(p_)+1][1] = __builtin_amdgcn_mfma_f32_16x16x32_bf16(a3_, bB11, acc[2*(p_)+1][1],0,0,0); \
    acc[2*(p_)+1][2] = __builtin_amdgcn_mfma_f32_16x16x32_bf16(a3_, bB21, acc[2*(p_)+1][2],0,0,0); \
    acc[2*(p_)+1][3] = __builtin_amdgcn_mfma_f32_16x16x32_bf16(a3_, bB31, acc[2*(p_)+1][3],0,0,0); \
    __builtin_amdgcn_s_setprio(0);                                                           \
    } while (0)

#define BAR()    __builtin_amdgcn_s_barrier()
#define SCHED0() __builtin_amdgcn_sched_barrier(0)
#define LGKM0()  asm volatile("s_waitcnt lgkmcnt(0)" ::: "memory")

    // prologue: stage all 4 units of tile 0; first 3 must land before p0 reads
    STAGEU(0, 0, 0); STAGEU(0, 0, 1); STAGEU(0, 0, 2); STAGEU(0, 0, 3);
    asm volatile("s_waitcnt vmcnt(2)" ::: "memory");
    BAR();

    bf16x8 bB00, bB01, bB10, bB11, bB20, bB21, bB30, bB31;
    bf16x8 a0_, a1_, a2_, a3_;

    #pragma unroll 1
    for (int c = 0; c < NT - 1; ++c) {
        const int buf = c & 1, nb = buf ^ 1;
        // ---- phase 0: read all B + A quadrant 0; stage Bh0(next) ----
        SCHED0();
        LDB(bB00, buf, 0, 0); LDB(bB01, buf, 0, 1);
        LDB(bB10, buf, 1, 0); LDB(bB11, buf, 1, 1);
        LDB(bB20, buf, 2, 0); LDB(bB21, buf, 2, 1);
        LDB(bB30, buf, 3, 0); LDB(bB31, buf, 3, 1);
        LDA(a0_, buf, 0, 0); LDA(a1_, buf, 0, 1); LDA(a2_, buf, 1, 0); LDA(a3_, buf, 1, 1);
        STAGEU(nb, c + 1, 0);
        BAR(); LGKM0(); SCHED0();
        MFMA16(0);
        // ---- phase 1: A quadrant 1; stage Bh1(next); wait for Ah1(cur) ----
        SCHED0();
        LDA(a0_, buf, 2, 0); LDA(a1_, buf, 2, 1); LDA(a2_, buf, 3, 0); LDA(a3_, buf, 3, 1);
        STAGEU(nb, c + 1, 1);
        asm volatile("s_waitcnt vmcnt(4)" ::: "memory");
        BAR(); LGKM0(); SCHED0();
        MFMA16(1);
        // ---- phase 2: A quadrant 2; stage Ah0(next) ----
        SCHED0();
        LDA(a0_, buf, 4, 0); LDA(a1_, buf, 4, 1); LDA(a2_, buf, 5, 0); LDA(a3_, buf, 5, 1);
        STAGEU(nb, c + 1, 2);
        BAR(); LGKM0(); SCHED0();
        MFMA16(2);
        // ---- phase 3: A quadrant 3; stage Ah1(next); wait for Bh0,Bh1,Ah0(next) ----
        SCHED0();
        LDA(a0_, buf, 6, 0); LDA(a1_, buf, 6, 1); LDA(a2_, buf, 7, 0); LDA(a3_, buf, 7, 1);
        STAGEU(nb, c + 1, 3);
        asm volatile("s_waitcnt vmcnt(2)" ::: "memory");
        BAR(); LGKM0(); SCHED0();
        MFMA16(3);
    }
    // ---- peeled tail tile (no stages); drain Ah1 with vmcnt(0) before quadrant 2 ----
    {
        const int buf = (NT - 1) & 1;
        SCHED0();
        LDB(bB00, buf, 0, 0); LDB(bB01, buf, 0, 1);
        LDB(bB10, buf, 1, 0); LDB(bB11, buf, 1, 1);
        LDB(bB20, buf, 2, 0); LDB(bB21, buf, 2, 1);
        LDB(bB30, buf, 3, 0); LDB(bB31, buf, 3, 1);
        LDA(a0_, buf, 0, 0); LDA(a1_, buf, 0, 1); LDA(a2_, buf, 1, 0); LDA(a3_, buf, 1, 1);
        BAR(); LGKM0(); SCHED0();
        MFMA16(0);
        SCHED0();
        LDA(a0_, buf, 2, 0); LDA(a1_, buf, 2, 1); LDA(a2_, buf, 3, 0); LDA(a3_, buf, 3, 1);
        asm volatile("s_waitcnt vmcnt(0)" ::: "memory");
        BAR(); LGKM0(); SCHED0();
        MFMA16(1);
        SCHED0();
        LDA(a0_, buf, 4, 0); LDA(a1_, buf, 4, 1); LDA(a2_, buf, 5, 0); LDA(a3_, buf, 5, 1);
        BAR(); LGKM0(); SCHED0();
        MFMA16(2);
        SCHED0();
        LDA(a0_, buf, 6, 0); LDA(a1_, buf, 6, 1); LDA(a2_, buf, 7, 0); LDA(a3_, buf, 7, 1);
        LGKM0(); SCHED0();
        MFMA16(3);
    }
#undef STAGEU
#undef LDA
#undef LDB
#undef MFMA16

    const float sc = scale_p[0];
    #pragma unroll
    for (int m = 0; m < 8; ++m) {
        #pragma unroll
        for (int j = 0; j < 4; ++j) {
            int co = co0 + m * 32 + wr * 16 + lhi * 4 + j;
            float bv = bias[co];
            size_t orow = ((size_t)b * COUT + co) * LEN + l0 + wc * 64;
            #pragma unroll
            for (int n = 0; n < 4; ++n)
                out[orow + n * 16 + llo] = sc * acc[m][n][j] + bv;
        }
    }
}

// ---- fallback (no x prepass) — only if ws too small ----
__global__ __launch_bounds__(256, 2) void conv_fb_kernel(
    const float* __restrict__ x,
    const unsigned short* __restrict__ wb,
    const float* __restrict__ scale_p,
    const float* __restrict__ bias,
    float* __restrict__ out)
{
    __shared__ char xT[132 * 128];
    const int bid = blockIdx.x;
    const int logical = (bid & 7) * 512 + (bid >> 3);
    const int co_tile = logical & 3;
    const int n_tile  = logical >> 2;
    const int b   = n_tile >> 6;
    const int l0  = (n_tile & 63) * 128;
    const int co0 = co_tile * 128;
    const int tid  = threadIdx.x;
    const int lane = tid & 63;
    const int wid  = tid >> 6;
    const int wr = wid >> 1, wc = wid & 1;
    const int lhi = lane >> 4;
    const int llo = lane & 15;
    f32x4 acc[4][4] = {};
    const float* xb = x + (size_t)b * CIN * LEN;

    for (int ci0 = 0; ci0 < CIN; ci0 += 64) {
        __syncthreads();
        for (int it = tid; it < 132 * 8; it += 256) {
            int c = it % 132;
            int o = it / 132;
            int l = l0 - 1 + c;
            float v[8];
            if (l >= 0 && l < LEN) {
                const float* src = xb + (size_t)(ci0 + o * 8) * LEN + l;
                #pragma unroll
                for (int j = 0; j < 8; ++j) v[j] = src[(size_t)j * LEN];
            } else {
                #pragma unroll
                for (int j = 0; j < 8; ++j) v[j] = 0.f;
            }
            union { bf16x8 v8; unsigned short s[8]; } pk;
            #pragma unroll
            for (int j = 0; j < 8; ++j) pk.s[j] = f2bf(v[j]);
            int byte = c * 128 + ((o * 16) ^ ((c & 7) << 4));
            *reinterpret_cast<bf16x8*>(xT + byte) = pk.v8;
        }
        __syncthreads();
        #pragma unroll
        for (int t = 0; t < KW; ++t) {
            #pragma unroll
            for (int s = 0; s < 2; ++s) {
                bf16x8 af[4];
                #pragma unroll
                for (int m = 0; m < 4; ++m)
                    af[m] = *reinterpret_cast<const bf16x8*>(
                        wb + (size_t)(co0 + wr * 64 + m * 16 + llo) * (KW * CIN)
                           + t * CIN + ci0 + s * 32 + 8 * lhi);
                bf16x8 bfr[4];
                #pragma unroll
                for (int n = 0; n < 4; ++n) {
                    int col = wc * 64 + n * 16 + llo + t;
                    int byte = col * 128 + (((s * 32 + 8 * lhi) * 2) ^ ((col & 7) << 4));
                    bfr[n] = *reinterpret_cast<const bf16x8*>(xT + byte);
                }
                #pragma unroll
                for (int m = 0; m < 4; ++m)
                    #pragma unroll
                    for (int n = 0; n < 4; ++n)
                        acc[m][n] = __builtin_amdgcn_mfma_f32_16x16x32_bf16(af[m], bfr[n], acc[m][n], 0, 0, 0);
            }
        }
    }
    const float sc = scale_p[0];
    #pragma unroll
    for (int m = 0; m < 4; ++m) {
        #pragma unroll
        for (int j = 0; j < 4; ++j) {
            int co = co0 + wr * 64 + m * 16 + lhi * 4 + j;
            float bv = bias[co];
            size_t orow = ((size_t)b * COUT + co) * LEN + l0 + wc * 64;
            #pragma unroll
            for (int n = 0; n < 4; ++n)
                out[orow + n * 16 + llo] = sc * acc[m][n][j] + bv;
        }
    }
}

extern "C" void kernel_launch(void* const* d_in, const int* in_sizes, int n_in,
                              void* d_out, int out_size, void* d_ws, size_t ws_size,
                              hipStream_t stream) {
    const float* x    = (const float*)d_in[0];
    const int*   qw   = (const int*)d_in[1];
    const float* sc   = (const float*)d_in[2];
    const float* bias = (const float*)d_in[3];
    float* out = (float*)d_out;
    unsigned short* wb = (unsigned short*)d_ws;

    wconv_kernel<<<(WB_ELEMS + 255) / 256, 256, 0, stream>>>(qw, wb);

    if (ws_size >= WB_BYTES + XS_BYTES) {
        unsigned short* xsw = (unsigned short*)((char*)d_ws + WB_BYTES);
        xprep_kernel<<<NB * 8 * (LEN / 64), 256, 0, stream>>>(x, xsw);
        conv_kernel<<<(COUT / BM2) * (NB * LEN / BN2), 512, 0, stream>>>(xsw, wb, sc, bias, out);
    } else {
        conv_fb_kernel<<<4096, 256, 0, stream>>>(x, wb, sc, bias, out);
    }
}

// Round 9
// 288.423 us; speedup vs baseline: 1.5813x; 1.0074x over previous
//
#include <hip/hip_runtime.h>
#include <hip/hip_bf16.h>

#define CIN   512
#define COUT  512
#define LEN   8192
#define NB    16
#define KW    3
#define PROWS 8200          // padded l-rows per batch (p = l+1)

#define WB_ELEMS (COUT * CIN * KW)
#define WB_BYTES ((size_t)WB_ELEMS * 2)
#define XS_BYTES ((size_t)NB * PROWS * CIN * 2)

#define BM2 256
#define BN2 256
#define BK3 64
#define NT  24               // K-tiles, tap innermost
#define TILE3 (BM2 * BK3 * 2)

typedef __attribute__((ext_vector_type(4))) float f32x4;
typedef __attribute__((ext_vector_type(8))) short bf16x8;

static __device__ __forceinline__ unsigned short f2bf(float f) {
    union { float f; unsigned u; } cv; cv.f = f;
    return (unsigned short)((cv.u + 0x7fffu + ((cv.u >> 16) & 1u)) >> 16);
}

// ---- weight dequant-reorder: qweight[co][ci][t] -> wb[co][t*512+ci] (bf16) ----
__global__ __launch_bounds__(256) void wconv_kernel(const int* __restrict__ q,
                                                    unsigned short* __restrict__ wb) {
    int idx = blockIdx.x * 256 + threadIdx.x;
    if (idx >= WB_ELEMS) return;
    int co = idx / (KW * CIN);
    int r  = idx - co * (KW * CIN);
    int t  = r >> 9;
    int ci = r & 511;
    wb[idx] = f2bf((float)q[(co * CIN + ci) * KW + t]);
}

// ---- x prepass: fp32 [b][ci][l] -> bf16 [b][1+l][ci]; zero halo rows ----
__global__ __launch_bounds__(256) void xprep_kernel(const float* __restrict__ x,
                                                    unsigned short* __restrict__ xs) {
    __shared__ char T[64 * 132];
    int blk = blockIdx.x;
    int b   = blk >> 10;
    int ci0 = ((blk >> 7) & 7) * 64;
    int l0  = (blk & 127) * 64;
    int tid = threadIdx.x;

    if (l0 == 0 && tid < 64)
        xs[((size_t)b * PROWS + 0) * CIN + ci0 + tid] = 0;
    if (l0 == (LEN - 64) && tid < 64)
        xs[((size_t)b * PROWS + (LEN + 1)) * CIN + ci0 + tid] = 0;

    const float* src = x + ((size_t)b * CIN + ci0) * LEN + l0;
    for (int i = tid; i < 64 * 16; i += 256) {
        int r = i >> 4, c4 = i & 15;
        f32x4 v = *(const f32x4*)(src + (size_t)r * LEN + c4 * 4);
        unsigned lo = (unsigned)f2bf(v[0]) | ((unsigned)f2bf(v[1]) << 16);
        unsigned hi = (unsigned)f2bf(v[2]) | ((unsigned)f2bf(v[3]) << 16);
        char* p = T + r * 132 + c4 * 8;
        *(unsigned*)p       = lo;
        *(unsigned*)(p + 4) = hi;
    }
    __syncthreads();
    unsigned short* dst = xs + ((size_t)b * PROWS + 1 + l0) * CIN + ci0;
    for (int i = tid; i < 64 * 8; i += 256) {
        int l = i >> 3, c8 = i & 7;
        union { bf16x8 v; unsigned short s[8]; } pk;
        #pragma unroll
        for (int j = 0; j < 8; ++j)
            pk.s[j] = *(const unsigned short*)(T + (c8 * 8 + j) * 132 + l * 2);
        *(bf16x8*)(dst + (size_t)l * CIN + c8 * 8) = pk.v;
    }
}

// ---- main conv: 8-phase, one-phase-ahead fragment reads, counted vmcnt ----
__global__ __launch_bounds__(512, 2) void conv_kernel(
    const unsigned short* __restrict__ xs,
    const unsigned short* __restrict__ wb,
    const float* __restrict__ scale_p,
    const float* __restrict__ bias,
    float* __restrict__ out)
{
    __shared__ char sA[2][TILE3];    // 2 x 32 KB
    __shared__ char sB[2][TILE3];    // 2 x 32 KB

    const int bid = blockIdx.x;
    const int logical = (bid & 7) * 128 + (bid >> 3);   // XCD swizzle
    const int co_tile = logical & 1;
    const int l_tile  = logical >> 1;
    const int b   = l_tile >> 5;
    const int l0  = (l_tile & 31) * BN2;
    const int co0 = co_tile * BM2;

    const int tid  = threadIdx.x;
    const int lane = tid & 63;
    const int wid  = tid >> 6;
    const int wr   = wid >> 2;
    const int wc   = wid & 3;
    const int lhi  = lane >> 4;
    const int llo  = lane & 15;

    f32x4 acc[8][4] = {};

    const char* xsB = (const char*)(xs + ((size_t)b * PROWS + l0) * CIN);
    const char* wbB = (const char*)wb + (size_t)co0 * (KW * CIN * 2);

    // per-thread 32-bit stage offsets (swizzled source, linear LDS dest)
    const int it0 = tid, it1 = tid + 512;
    const int r0 = it0 >> 3, r1 = it1 >> 3;
    const int sw0 = ((it0 & 7) * 16) ^ ((r0 & 7) << 4);
    const int sw1 = ((it1 & 7) * 16) ^ ((r1 & 7) << 4);
    const int vB0 = r0 * 1024 + sw0, vB1 = r1 * 1024 + sw1;
    const int vA0 = r0 * 3072 + sw0, vA1 = r1 * 3072 + sw1;
    const int d0  = tid * 16;

    // LDS read bases (buf0); buf1 via +32768 compile-time immediate
    const int s10 = llo & 3, s2 = (llo >> 2) & 1;
    const int constA = (wr * 16 + llo) * 128 + ((lhi ^ s10) << 4);
    const int constB = (wc * 64 + llo) * 128 + ((lhi ^ s10) << 4);
    const char* pA0 = &sA[0][0] + constA + (s2 ? 64 : 0);   // A k=0
    const char* pA1 = &sA[0][0] + constA + (s2 ? 0 : 64);   // A k=1
    const char* pB0 = &sB[0][0] + constB + (s2 ? 64 : 0);   // B k=0
    const char* pB1 = &sB[0][0] + constB + (s2 ? 0 : 64);   // B k=1

#define GL(src_, dst_) __builtin_amdgcn_global_load_lds(                                     \
    (const __attribute__((address_space(1))) unsigned int*)(src_),                           \
    (__attribute__((address_space(3))) unsigned int*)(dst_), 16, 0, 0)

#define STAGEU(BUF, u_, koff_) do {                                                          \
    if ((u_) == 0)      { const char* s_ = xsB + (koff_);                                    \
        GL(s_ + vB0, &sB[BUF][0] + d0);      GL(s_ + vB1, &sB[BUF][0] + d0 + 8192); }        \
    else if ((u_) == 1) { const char* s_ = xsB + (koff_) + 131072;                           \
        GL(s_ + vB0, &sB[BUF][16384] + d0);  GL(s_ + vB1, &sB[BUF][16384] + d0 + 8192); }    \
    else if ((u_) == 2) { const char* s_ = wbB + (koff_);                                    \
        GL(s_ + vA0, &sA[BUF][0] + d0);      GL(s_ + vA1, &sA[BUF][0] + d0 + 8192); }        \
    else                { const char* s_ = wbB + (koff_) + 393216;                           \
        GL(s_ + vA0, &sA[BUF][16384] + d0);  GL(s_ + vA1, &sA[BUF][16384] + d0 + 8192); }    \
    } while (0)

#define RA(BUF, k_, mq_) (*(const bf16x8*)(((k_) ? pA1 : pA0) + (BUF) * 32768 + (mq_) * 4096))
#define RB(BUF, k_, n_)  (*(const bf16x8*)(((k_) ? pB1 : pB0) + (BUF) * 32768 + (n_) * 2048))

#define MFMA16(mb_, A0_, A1_, A2_, A3_, B0_, B1_, B2_, B3_) do {                             \
    __builtin_amdgcn_s_setprio(1);                                                           \
    acc[(mb_)+0][0] = __builtin_amdgcn_mfma_f32_16x16x32_bf16(A0_, B0_, acc[(mb_)+0][0],0,0,0); \
    acc[(mb_)+0][1] = __builtin_amdgcn_mfma_f32_16x16x32_bf16(A0_, B1_, acc[(mb_)+0][1],0,0,0); \
    acc[(mb_)+0][2] = __builtin_amdgcn_mfma_f32_16x16x32_bf16(A0_, B2_, acc[(mb_)+0][2],0,0,0); \
    acc[(mb_)+0][3] = __builtin_amdgcn_mfma_f32_16x16x32_bf16(A0_, B3_, acc[(mb_)+0][3],0,0,0); \
    acc[(mb_)+1][0] = __builtin_amdgcn_mfma_f32_16x16x32_bf16(A1_, B0_, acc[(mb_)+1][0],0,0,0); \
    acc[(mb_)+1][1] = __builtin_amdgcn_mfma_f32_16x16x32_bf16(A1_, B1_, acc[(mb_)+1][1],0,0,0); \
    acc[(mb_)+1][2] = __builtin_amdgcn_mfma_f32_16x16x32_bf16(A1_, B2_, acc[(mb_)+1][2],0,0,0); \
    acc[(mb_)+1][3] = __builtin_amdgcn_mfma_f32_16x16x32_bf16(A1_, B3_, acc[(mb_)+1][3],0,0,0); \
    acc[(mb_)+2][0] = __builtin_amdgcn_mfma_f32_16x16x32_bf16(A2_, B0_, acc[(mb_)+2][0],0,0,0); \
    acc[(mb_)+2][1] = __builtin_amdgcn_mfma_f32_16x16x32_bf16(A2_, B1_, acc[(mb_)+2][1],0,0,0); \
    acc[(mb_)+2][2] = __builtin_amdgcn_mfma_f32_16x16x32_bf16(A2_, B2_, acc[(mb_)+2][2],0,0,0); \
    acc[(mb_)+2][3] = __builtin_amdgcn_mfma_f32_16x16x32_bf16(A2_, B3_, acc[(mb_)+2][3],0,0,0); \
    acc[(mb_)+3][0] = __builtin_amdgcn_mfma_f32_16x16x32_bf16(A3_, B0_, acc[(mb_)+3][0],0,0,0); \
    acc[(mb_)+3][1] = __builtin_amdgcn_mfma_f32_16x16x32_bf16(A3_, B1_, acc[(mb_)+3][1],0,0,0); \
    acc[(mb_)+3][2] = __builtin_amdgcn_mfma_f32_16x16x32_bf16(A3_, B2_, acc[(mb_)+3][2],0,0,0); \
    acc[(mb_)+3][3] = __builtin_amdgcn_mfma_f32_16x16x32_bf16(A3_, B3_, acc[(mb_)+3][3],0,0,0); \
    __builtin_amdgcn_s_setprio(0);                                                           \
    } while (0)

#define BAR()    __builtin_amdgcn_s_barrier()
#define SCHED0() __builtin_amdgcn_sched_barrier(0)
#define FENCE()  asm volatile("" ::: "memory")

    // fragment registers: A quads ping-pong (aA/aB); B sets bX=k0, bY=k1
    bf16x8 aA0, aA1, aA2, aA3, aB0, aB1, aB2, aB3;
    bf16x8 bX0, bX1, bX2, bX3, bY0, bY1, bY2, bY3;

    // prologue: stage tile 0; publish u0-u2; preload p0 fragments
    STAGEU(0, 0, 0); STAGEU(0, 1, 0); STAGEU(0, 2, 0); STAGEU(0, 3, 0);
    int koff = 1024, tapn = 1;        // offsets/tap of tile 1 (next staged)
    asm volatile("s_waitcnt vmcnt(2)" ::: "memory");
    BAR(); FENCE(); SCHED0();
    aA0 = RA(0,0,0); aA1 = RA(0,0,1); aA2 = RA(0,0,2); aA3 = RA(0,0,3);
    bX0 = RB(0,0,0); bX1 = RB(0,0,1); bX2 = RB(0,0,2); bX3 = RB(0,0,3);

    // TILE: phase p reads frags for phase p+1 (post-BAR), MFMAs on prev-phase regs
#define TILE(BUF, NBUF) do {                                                                 \
    /* p0 */                                                                                 \
    STAGEU(NBUF, 0, koff);                                                                   \
    BAR(); FENCE(); SCHED0();                                                                \
    aB0 = RA(BUF,1,0); aB1 = RA(BUF,1,1); aB2 = RA(BUF,1,2); aB3 = RA(BUF,1,3);              \
    bY0 = RB(BUF,1,0); bY1 = RB(BUF,1,1); bY2 = RB(BUF,1,2); bY3 = RB(BUF,1,3);              \
    SCHED0();                                                                                \
    MFMA16(0, aA0, aA1, aA2, aA3, bX0, bX1, bX2, bX3);                                       \
    /* p1 */                                                                                 \
    STAGEU(NBUF, 1, koff);                                                                   \
    asm volatile("s_waitcnt vmcnt(4)" ::: "memory");                                         \
    BAR(); FENCE(); SCHED0();                                                                \
    aA0 = RA(BUF,0,4); aA1 = RA(BUF,0,5); aA2 = RA(BUF,0,6); aA3 = RA(BUF,0,7);              \
    SCHED0();                                                                                \
    MFMA16(0, aB0, aB1, aB2, aB3, bY0, bY1, bY2, bY3);                                       \
    /* p2 */                                                                                 \
    STAGEU(NBUF, 2, koff);                                                                   \
    BAR(); FENCE(); SCHED0();                                                                \
    aB0 = RA(BUF,1,4); aB1 = RA(BUF,1,5); aB2 = RA(BUF,1,6); aB3 = RA(BUF,1,7);              \
    SCHED0();                                                                                \
    MFMA16(4, aA0, aA1, aA2, aA3, bX0, bX1, bX2, bX3);                                       \
    /* p3 */                                                                                 \
    STAGEU(NBUF, 3, koff);                                                                   \
    asm volatile("s_waitcnt vmcnt(2)" ::: "memory");                                         \
    BAR(); FENCE(); SCHED0();                                                                \
    aA0 = RA(NBUF,0,0); aA1 = RA(NBUF,0,1); aA2 = RA(NBUF,0,2); aA3 = RA(NBUF,0,3);          \
    bX0 = RB(NBUF,0,0); bX1 = RB(NBUF,0,1); bX2 = RB(NBUF,0,2); bX3 = RB(NBUF,0,3);          \
    SCHED0();                                                                                \
    MFMA16(4, aB0, aB1, aB2, aB3, bY0, bY1, bY2, bY3);                                       \
    koff += (tapn == 2) ? -1920 : 1024;                                                      \
    tapn  = (tapn == 2) ? 0 : tapn + 1;                                                      \
    } while (0)

    #pragma unroll 1
    for (int cc = 0; cc < 11; ++cc) {    // tiles 0..21
        TILE(0, 1);
        TILE(1, 0);
    }
    TILE(0, 1);                          // tile 22 (stages tile 23 into buf1)
    // ---- tail: tile 23 (buf1), no stages ----
    {
        BAR(); FENCE(); SCHED0();
        aB0 = RA(1,1,0); aB1 = RA(1,1,1); aB2 = RA(1,1,2); aB3 = RA(1,1,3);
        bY0 = RB(1,1,0); bY1 = RB(1,1,1); bY2 = RB(1,1,2); bY3 = RB(1,1,3);
        SCHED0();
        MFMA16(0, aA0, aA1, aA2, aA3, bX0, bX1, bX2, bX3);
        asm volatile("s_waitcnt vmcnt(0)" ::: "memory");
        BAR(); FENCE(); SCHED0();
        aA0 = RA(1,0,4); aA1 = RA(1,0,5); aA2 = RA(1,0,6); aA3 = RA(1,0,7);
        SCHED0();
        MFMA16(0, aB0, aB1, aB2, aB3, bY0, bY1, bY2, bY3);
        SCHED0();
        aB0 = RA(1,1,4); aB1 = RA(1,1,5); aB2 = RA(1,1,6); aB3 = RA(1,1,7);
        SCHED0();
        MFMA16(4, aA0, aA1, aA2, aA3, bX0, bX1, bX2, bX3);
        SCHED0();
        MFMA16(4, aB0, aB1, aB2, aB3, bY0, bY1, bY2, bY3);
    }
#undef TILE
#undef STAGEU
#undef GL
#undef RA
#undef RB
#undef MFMA16

    const float sc = scale_p[0];
    #pragma unroll
    for (int m = 0; m < 8; ++m) {
        #pragma unroll
        for (int j = 0; j < 4; ++j) {
            int co = co0 + m * 32 + wr * 16 + lhi * 4 + j;
            float bv = bias[co];
            size_t orow = ((size_t)b * COUT + co) * LEN + l0 + wc * 64;
            #pragma unroll
            for (int n = 0; n < 4; ++n)
                out[orow + n * 16 + llo] = sc * acc[m][n][j] + bv;
        }
    }
}

// ---- fallback (no x prepass) — only if ws too small ----
__global__ __launch_bounds__(256, 2) void conv_fb_kernel(
    const float* __restrict__ x,
    const unsigned short* __restrict__ wb,
    const float* __restrict__ scale_p,
    const float* __restrict__ bias,
    float* __restrict__ out)
{
    __shared__ char xT[132 * 128];
    const int bid = blockIdx.x;
    const int logical = (bid & 7) * 512 + (bid >> 3);
    const int co_tile = logical & 3;
    const int n_tile  = logical >> 2;
    const int b   = n_tile >> 6;
    const int l0  = (n_tile & 63) * 128;
    const int co0 = co_tile * 128;
    const int tid  = threadIdx.x;
    const int lane = tid & 63;
    const int wid  = tid >> 6;
    const int wr = wid >> 1, wc = wid & 1;
    const int lhi = lane >> 4;
    const int llo = lane & 15;
    f32x4 acc[4][4] = {};
    const float* xb = x + (size_t)b * CIN * LEN;

    for (int ci0 = 0; ci0 < CIN; ci0 += 64) {
        __syncthreads();
        for (int it = tid; it < 132 * 8; it += 256) {
            int c = it % 132;
            int o = it / 132;
            int l = l0 - 1 + c;
            float v[8];
            if (l >= 0 && l < LEN) {
                const float* src = xb + (size_t)(ci0 + o * 8) * LEN + l;
                #pragma unroll
                for (int j = 0; j < 8; ++j) v[j] = src[(size_t)j * LEN];
            } else {
                #pragma unroll
                for (int j = 0; j < 8; ++j) v[j] = 0.f;
            }
            union { bf16x8 v8; unsigned short s[8]; } pk;
            #pragma unroll
            for (int j = 0; j < 8; ++j) pk.s[j] = f2bf(v[j]);
            int byte = c * 128 + ((o * 16) ^ ((c & 7) << 4));
            *reinterpret_cast<bf16x8*>(xT + byte) = pk.v8;
        }
        __syncthreads();
        #pragma unroll
        for (int t = 0; t < KW; ++t) {
            #pragma unroll
            for (int s = 0; s < 2; ++s) {
                bf16x8 af[4];
                #pragma unroll
                for (int m = 0; m < 4; ++m)
                    af[m] = *reinterpret_cast<const bf16x8*>(
                        wb + (size_t)(co0 + wr * 64 + m * 16 + llo) * (KW * CIN)
                           + t * CIN + ci0 + s * 32 + 8 * lhi);
                bf16x8 bfr[4];
                #pragma unroll
                for (int n = 0; n < 4; ++n) {
                    int col = wc * 64 + n * 16 + llo + t;
                    int byte = col * 128 + (((s * 32 + 8 * lhi) * 2) ^ ((col & 7) << 4));
                    bfr[n] = *reinterpret_cast<const bf16x8*>(xT + byte);
                }
                #pragma unroll
                for (int m = 0; m < 4; ++m)
                    #pragma unroll
                    for (int n = 0; n < 4; ++n)
                        acc[m][n] = __builtin_amdgcn_mfma_f32_16x16x32_bf16(af[m], bfr[n], acc[m][n], 0, 0, 0);
            }
        }
    }
    const float sc = scale_p[0];
    #pragma unroll
    for (int m = 0; m < 4; ++m) {
        #pragma unroll
        for (int j = 0; j < 4; ++j) {
            int co = co0 + wr * 64 + m * 16 + lhi * 4 + j;
            float bv = bias[co];
            size_t orow = ((size_t)b * COUT + co) * LEN + l0 + wc * 64;
            #pragma unroll
            for (int n = 0; n < 4; ++n)
                out[orow + n * 16 + llo] = sc * acc[m][n][j] + bv;
        }
    }
}

extern "C" void kernel_launch(void* const* d_in, const int* in_sizes, int n_in,
                              void* d_out, int out_size, void* d_ws, size_t ws_size,
                              hipStream_t stream) {
    const float* x    = (const float*)d_in[0];
    const int*   qw   = (const int*)d_in[1];
    const float* sc   = (const float*)d_in[2];
    const float* bias = (const float*)d_in[3];
    float* out = (float*)d_out;
    unsigned short* wb = (unsigned short*)d_ws;

    wconv_kernel<<<(WB_ELEMS + 255) / 256, 256, 0, stream>>>(qw, wb);

    if (ws_size >= WB_BYTES + XS_BYTES) {
        unsigned short* xsw = (unsigned short*)((char*)d_ws + WB_BYTES);
        xprep_kernel<<<NB * 8 * (LEN / 64), 256, 0, stream>>>(x, xsw);
        conv_kernel<<<(COUT / BM2) * (NB * LEN / BN2), 512, 0, stream>>>(xsw, wb, sc, bias, out);
    } else {
        conv_fb_kernel<<<4096, 256, 0, stream>>>(x, wb, sc, bias, out);
    }
}

// Round 10
// 282.432 us; speedup vs baseline: 1.6149x; 1.0212x over previous
//
#include <hip/hip_runtime.h>
#include <hip/hip_bf16.h>

#define CIN   512
#define COUT  512
#define LEN   8192
#define NB    16
#define KW    3

#define WB_ELEMS (COUT * CIN * KW)
#define WB_BYTES ((size_t)WB_ELEMS * 2)

#define PNL_ROWS 258
#define PNL_B (PNL_ROWS * 128)      // 33024 B per x-panel (258 l-rows x 64 ci bf16)

typedef __attribute__((ext_vector_type(4))) float f32x4;
typedef __attribute__((ext_vector_type(8))) short bf16x8;

static __device__ __forceinline__ unsigned short f2bf(float f) {
    union { float f; unsigned u; } cv; cv.f = f;
    return (unsigned short)((cv.u + 0x7fffu + ((cv.u >> 16) & 1u)) >> 16);
}

// ---- weight dequant-reorder: qweight[co][ci][t] -> wb[co][t*512+ci] (bf16) ----
__global__ __launch_bounds__(256) void wconv_kernel(const int* __restrict__ q,
                                                    unsigned short* __restrict__ wb) {
    int idx = blockIdx.x * 256 + threadIdx.x;
    if (idx >= WB_ELEMS) return;
    int co = idx / (KW * CIN);
    int r  = idx - co * (KW * CIN);
    int t  = r >> 9;
    int ci = r & 511;
    wb[idx] = f2bf((float)q[(co * CIN + ci) * KW + t]);
}

// ---- fused conv: x transposed+converted in-kernel; one panel serves all 3 taps ----
__global__ __launch_bounds__(512, 2) void conv_kernel(
    const float* __restrict__ x,
    const unsigned short* __restrict__ wb,
    const float* __restrict__ scale_p,
    const float* __restrict__ bias,
    float* __restrict__ out)
{
    __shared__ char sA[2][32768];     // A (weights) dbuf, 256 rows x 64k bf16, XOR-swz
    __shared__ char sP[2][PNL_B];     // x panels: [258 l-rows][64 ci] bf16, XOR-swz

    const int bid = blockIdx.x;
    const int logical = (bid & 7) * 128 + (bid >> 3);   // XCD swizzle; co-pair shares L2
    const int co_tile = logical & 1;
    const int l_tile  = logical >> 1;
    const int b   = l_tile >> 5;
    const int l0  = (l_tile & 31) * 256;
    const int co0 = co_tile * 256;

    const int tid  = threadIdx.x;
    const int lane = tid & 63;
    const int wid  = tid >> 6;
    const int wr   = wid >> 2;
    const int wc   = wid & 3;
    const int lhi  = lane >> 4;
    const int llo  = lane & 15;

    f32x4 acc[8][4] = {};

    // ---- A staging consts (gload_lds, swizzled source, linear LDS dest) ----
    const char* wbB = (const char*)wb + (size_t)co0 * (KW * CIN * 2);
    const int rA_r  = tid >> 3;
    const int rA_sw = ((tid & 7) * 16) ^ ((rA_r & 7) << 4);
    const char* aS  = wbB + (size_t)rA_r * 3072 + rA_sw;
    const int d0 = tid * 16;
    char* const sA0 = &sA[0][0];
    char* const sP0 = &sP[0][0];

    // ---- A read consts ----
    const int s10 = llo & 3, s2 = (llo >> 2) & 1;
    const int cA  = (wr * 16 + llo) * 128 + ((lhi ^ s10) << 4);
    const int cA0 = cA + (s2 ? 64 : 0);
    const int cA1 = cA + (s2 ? 0 : 64);

    // ---- B (x) staging consts: wave wid stages ci quad cq*4; lane -> l row ----
    const int cq = wid;                            // 0..7
    const float* xb = x + (size_t)b * CIN * LEN;
    const int lbase = l0 - 1 + lane;               // l for row = lane (s=0)

#define BAR()    __builtin_amdgcn_s_barrier()
#define SCHED0() __builtin_amdgcn_sched_barrier(0)
#define LGKM0()  asm volatile("s_waitcnt lgkmcnt(0)" ::: "memory")
#define BARMID() do { BAR(); LGKM0(); SCHED0(); } while (0)

#define AGL(i_, ko_, an_) __builtin_amdgcn_global_load_lds(                                  \
    (const __attribute__((address_space(1))) unsigned int*)(aS + (ko_) + (i_) * 196608),     \
    (__attribute__((address_space(3))) unsigned int*)(sA0 + (an_) + d0 + (i_) * 8192),       \
    16, 0, 0)

#define RA(P_, mq_) (*(const bf16x8*)((P_) + (mq_) * 4096))
#define RB(P_, n_)  (*(const bf16x8*)((P_) + (n_) * 2048))

// load 4 ci-rows x 1 l for unit (S,H) into V0..V3 (zeros at halo / beyond panel)
#define BLOAD(S_, H_, V0_, V1_, V2_, V3_, XP_) do {                                          \
    int row_ = lane + (S_) * 64;                                                             \
    int l_   = lbase + (S_) * 64;                                                            \
    V0_ = 0.f; V1_ = 0.f; V2_ = 0.f; V3_ = 0.f;                                              \
    if ((row_ < PNL_ROWS) && ((unsigned)l_ < (unsigned)LEN)) {                               \
        const float* p_ = (XP_) + (size_t)((H_) * 32 + cq * 4) * LEN + l_;                   \
        V0_ = p_[0]; V1_ = p_[LEN]; V2_ = p_[2 * LEN]; V3_ = p_[3 * LEN];                    \
    } } while (0)

#define BPACKW(S_, H_, V0_, V1_, V2_, V3_, PD_) do {                                         \
    int row_ = lane + (S_) * 64;                                                             \
    if (row_ < PNL_ROWS) {                                                                   \
        uint2 w_;                                                                            \
        w_.x = (unsigned)f2bf(V0_) | ((unsigned)f2bf(V1_) << 16);                            \
        w_.y = (unsigned)f2bf(V2_) | ((unsigned)f2bf(V3_) << 16);                            \
        *(uint2*)((PD_) + row_ * 128 + ((((H_) * 64) + cq * 8) ^ ((row_ & 7) << 4))) = w_;   \
    } } while (0)

#define MFMA16(mb_, A0_, A1_, A2_, A3_, B0_, B1_, B2_, B3_) do {                             \
    __builtin_amdgcn_s_setprio(1);                                                           \
    acc[(mb_)+0][0] = __builtin_amdgcn_mfma_f32_16x16x32_bf16(A0_, B0_, acc[(mb_)+0][0],0,0,0); \
    acc[(mb_)+0][1] = __builtin_amdgcn_mfma_f32_16x16x32_bf16(A0_, B1_, acc[(mb_)+0][1],0,0,0); \
    acc[(mb_)+0][2] = __builtin_amdgcn_mfma_f32_16x16x32_bf16(A0_, B2_, acc[(mb_)+0][2],0,0,0); \
    acc[(mb_)+0][3] = __builtin_amdgcn_mfma_f32_16x16x32_bf16(A0_, B3_, acc[(mb_)+0][3],0,0,0); \
    acc[(mb_)+1][0] = __builtin_amdgcn_mfma_f32_16x16x32_bf16(A1_, B0_, acc[(mb_)+1][0],0,0,0); \
    acc[(mb_)+1][1] = __builtin_amdgcn_mfma_f32_16x16x32_bf16(A1_, B1_, acc[(mb_)+1][1],0,0,0); \
    acc[(mb_)+1][2] = __builtin_amdgcn_mfma_f32_16x16x32_bf16(A1_, B2_, acc[(mb_)+1][2],0,0,0); \
    acc[(mb_)+1][3] = __builtin_amdgcn_mfma_f32_16x16x32_bf16(A1_, B3_, acc[(mb_)+1][3],0,0,0); \
    acc[(mb_)+2][0] = __builtin_amdgcn_mfma_f32_16x16x32_bf16(A2_, B0_, acc[(mb_)+2][0],0,0,0); \
    acc[(mb_)+2][1] = __builtin_amdgcn_mfma_f32_16x16x32_bf16(A2_, B1_, acc[(mb_)+2][1],0,0,0); \
    acc[(mb_)+2][2] = __builtin_amdgcn_mfma_f32_16x16x32_bf16(A2_, B2_, acc[(mb_)+2][2],0,0,0); \
    acc[(mb_)+2][3] = __builtin_amdgcn_mfma_f32_16x16x32_bf16(A2_, B3_, acc[(mb_)+2][3],0,0,0); \
    acc[(mb_)+3][0] = __builtin_amdgcn_mfma_f32_16x16x32_bf16(A3_, B0_, acc[(mb_)+3][0],0,0,0); \
    acc[(mb_)+3][1] = __builtin_amdgcn_mfma_f32_16x16x32_bf16(A3_, B1_, acc[(mb_)+3][1],0,0,0); \
    acc[(mb_)+3][2] = __builtin_amdgcn_mfma_f32_16x16x32_bf16(A3_, B2_, acc[(mb_)+3][2],0,0,0); \
    acc[(mb_)+3][3] = __builtin_amdgcn_mfma_f32_16x16x32_bf16(A3_, B3_, acc[(mb_)+3][3],0,0,0); \
    __builtin_amdgcn_s_setprio(0);                                                           \
    } while (0)

// One tap-tile = 4 phases.  Args: T=tap, AC/AN = cur/next A-buf byte offset,
// KO = A src offset of the tile being staged, (PSp,PHp,LSp,LHp) = pack/load unit
// per phase (-1 = none; loads/packs at p0,p2 use e-set, p1,p3 use o-set),
// VM3 = vmcnt at p3 (-1 none), ENDCH = lgkm-drain BEFORE the p3 barrier
// (panel publication), DOA = do A-gloads.
#define TAPS(T_, AC_, AN_, KO_, PS0,PH0,LS0,LH0, PS1,PH1,LS1,LH1,                            \
             PS2,PH2,LS2,LH2, PS3,PH3,LS3,LH3, VM3_, ENDCH_, DOA_) do {                      \
    const int e7_ = (llo + (T_)) & 7;                                                        \
    const int rwb_ = (wc * 64 + llo + (T_)) * 128;                                           \
    const char* rB0_ = pbR + rwb_ + ((lhi * 16) ^ (e7_ << 4));                               \
    const char* rB1_ = pbR + rwb_ + (((lhi * 16) + 64) ^ (e7_ << 4));                        \
    const char* rA0_ = sA0 + (AC_) + cA0;                                                    \
    const char* rA1_ = sA0 + (AC_) + cA1;                                                    \
    /* p0 */                                                                                 \
    SCHED0();                                                                                \
    if ((PS0) >= 0) BPACKW(PS0, PH0, e0, e1, e2, e3, pbW);                                   \
    if (DOA_) { AGL(0, (KO_), (AN_)); AGL(1, (KO_), (AN_)); }                                \
    if ((LS0) >= 0) BLOAD(LS0, LH0, e0, e1, e2, e3, xn);                                     \
    bX0 = RB(rB0_, 0); bX1 = RB(rB0_, 1); bX2 = RB(rB0_, 2); bX3 = RB(rB0_, 3);              \
    bY0 = RB(rB1_, 0); bY1 = RB(rB1_, 1); bY2 = RB(rB1_, 2); bY3 = RB(rB1_, 3);              \
    a0 = RA(rA0_, 0); a1 = RA(rA0_, 1); a2 = RA(rA0_, 2); a3 = RA(rA0_, 3);                  \
    BARMID();                                                                                \
    MFMA16(0, a0, a1, a2, a3, bX0, bX1, bX2, bX3);                                           \
    /* p1 */                                                                                 \
    SCHED0();                                                                                \
    if ((PS1) >= 0) BPACKW(PS1, PH1, o0, o1, o2, o3, pbW);                                   \
    if (DOA_) { AGL(2, (KO_), (AN_)); AGL(3, (KO_), (AN_)); }                                \
    if ((LS1) >= 0) BLOAD(LS1, LH1, o0, o1, o2, o3, xn);                                     \
    a0 = RA(rA1_, 0); a1 = RA(rA1_, 1); a2 = RA(rA1_, 2); a3 = RA(rA1_, 3);                  \
    BARMID();                                                                                \
    MFMA16(0, a0, a1, a2, a3, bY0, bY1, bY2, bY3);                                           \
    /* p2 */                                                                                 \
    SCHED0();                                                                                \
    if ((PS2) >= 0) BPACKW(PS2, PH2, e0, e1, e2, e3, pbW);                                   \
    if ((LS2) >= 0) BLOAD(LS2, LH2, e0, e1, e2, e3, xn);                                     \
    a0 = RA(rA0_, 4); a1 = RA(rA0_, 5); a2 = RA(rA0_, 6); a3 = RA(rA0_, 7);                  \
    BARMID();                                                                                \
    MFMA16(4, a0, a1, a2, a3, bX0, bX1, bX2, bX3);                                           \
    /* p3 */                                                                                 \
    SCHED0();                                                                                \
    if ((PS3) >= 0) BPACKW(PS3, PH3, o0, o1, o2, o3, pbW);                                   \
    if ((LS3) >= 0) BLOAD(LS3, LH3, o0, o1, o2, o3, xn);                                     \
    a0 = RA(rA1_, 4); a1 = RA(rA1_, 5); a2 = RA(rA1_, 6); a3 = RA(rA1_, 7);                  \
    if ((VM3_) == 12)     asm volatile("s_waitcnt vmcnt(12)" ::: "memory");                  \
    else if ((VM3_) == 4) asm volatile("s_waitcnt vmcnt(4)"  ::: "memory");                  \
    else if ((VM3_) == 0) asm volatile("s_waitcnt vmcnt(0)"  ::: "memory");                  \
    if (ENDCH_) { LGKM0(); BAR(); SCHED0(); } else { BARMID(); }                             \
    MFMA16(4, a0, a1, a2, a3, bY0, bY1, bY2, bY3);                                           \
    } while (0)

    bf16x8 a0, a1, a2, a3;
    bf16x8 bX0, bX1, bX2, bX3, bY0, bY1, bY2, bY3;
    float e0, e1, e2, e3, o0, o1, o2, o3;

    // ---------- prologue: stage A tile0 + full x-panel of chunk 0 ----------
    {
        const float* xn = xb;          // chunk 0 (ci base 0)
        char* pbW = sP0;               // panel 0
        float f0, f1, f2, f3, g0, g1, g2, g3;
        BLOAD(0, 0, e0, e1, e2, e3, xn);
        BLOAD(0, 1, o0, o1, o2, o3, xn);
        BLOAD(1, 0, f0, f1, f2, f3, xn);
        BLOAD(1, 1, g0, g1, g2, g3, xn);
        AGL(0, 0, 0); AGL(1, 0, 0); AGL(2, 0, 0); AGL(3, 0, 0);
        BPACKW(0, 0, e0, e1, e2, e3, pbW); BLOAD(2, 0, e0, e1, e2, e3, xn);
        BPACKW(0, 1, o0, o1, o2, o3, pbW); BLOAD(2, 1, o0, o1, o2, o3, xn);
        BPACKW(1, 0, f0, f1, f2, f3, pbW); BLOAD(3, 0, f0, f1, f2, f3, xn);
        BPACKW(1, 1, g0, g1, g2, g3, pbW); BLOAD(3, 1, g0, g1, g2, g3, xn);
        BPACKW(2, 0, e0, e1, e2, e3, pbW); BLOAD(4, 0, e0, e1, e2, e3, xn);
        BPACKW(2, 1, o0, o1, o2, o3, pbW); BLOAD(4, 1, o0, o1, o2, o3, xn);
        BPACKW(3, 0, f0, f1, f2, f3, pbW);
        BPACKW(3, 1, g0, g1, g2, g3, pbW);
        BPACKW(4, 0, e0, e1, e2, e3, pbW);
        BPACKW(4, 1, o0, o1, o2, o3, pbW);
        asm volatile("s_waitcnt vmcnt(0)" ::: "memory");
        LGKM0();
        BAR();
    }

    int koff = 1024;                   // A src offset of next-staged tile (tile 1)
    #pragma unroll 1
    for (int q = 0; q < 7; ++q) {
        const int p_    = q & 1;
        const int abufC = p_ << 15;
        const int abufN = abufC ^ 32768;
        const char* pbR = sP0 + p_ * PNL_B;
        char*       pbW = sP0 + (p_ ^ 1) * PNL_B;
        const float* xn = xb + (size_t)(q + 1) * 64 * LEN;

        TAPS(0, abufC, abufN, koff,
             -1,0, 0,0,   -1,0, 0,1,   0,0, 1,0,   0,1, 1,1,   12, 0, 1);
        TAPS(1, abufN, abufC, koff + 1024,
              1,0, 2,0,    1,1, 2,1,   2,0, 3,0,   2,1, 3,1,   12, 0, 1);
        TAPS(2, abufC, abufN, koff - 896,
              3,0, 4,0,    3,1, 4,1,   4,0,-1,0,   4,1,-1,0,    4, 1, 1);
        koff += 128;
    }
    // ---------- tail chunk q=7 (reads panel 1; no B staging) ----------
    {
        const char* pbR = sP0 + PNL_B;
        char*       pbW = sP0;         // unused
        const float* xn = xb;          // unused
        TAPS(0, 32768, 0, koff,
             -1,0,-1,0,  -1,0,-1,0,  -1,0,-1,0,  -1,0,-1,0,   0, 0, 1);
        TAPS(1, 0, 32768, koff + 1024,
             -1,0,-1,0,  -1,0,-1,0,  -1,0,-1,0,  -1,0,-1,0,   0, 0, 1);
        TAPS(2, 32768, 0, 0,
             -1,0,-1,0,  -1,0,-1,0,  -1,0,-1,0,  -1,0,-1,0,  -1, 0, 0);
    }
#undef TAPS
#undef AGL
#undef RA
#undef RB
#undef BLOAD
#undef BPACKW
#undef MFMA16

    const float sc = scale_p[0];
    #pragma unroll
    for (int m = 0; m < 8; ++m) {
        #pragma unroll
        for (int j = 0; j < 4; ++j) {
            int co = co0 + m * 32 + wr * 16 + lhi * 4 + j;
            float bv = bias[co];
            size_t orow = ((size_t)b * COUT + co) * LEN + l0 + wc * 64;
            #pragma unroll
            for (int n = 0; n < 4; ++n)
                out[orow + n * 16 + llo] = sc * acc[m][n][j] + bv;
        }
    }
}

extern "C" void kernel_launch(void* const* d_in, const int* in_sizes, int n_in,
                              void* d_out, int out_size, void* d_ws, size_t ws_size,
                              hipStream_t stream) {
    const float* x    = (const float*)d_in[0];
    const int*   qw   = (const int*)d_in[1];
    const float* sc   = (const float*)d_in[2];
    const float* bias = (const float*)d_in[3];
    float* out = (float*)d_out;
    unsigned short* wb = (unsigned short*)d_ws;   // 1.5 MB

    wconv_kernel<<<(WB_ELEMS + 255) / 256, 256, 0, stream>>>(qw, wb);
    conv_kernel<<<1024, 512, 0, stream>>>(x, wb, sc, bias, out);
}